// Round 3
// baseline (593.164 us; speedup 1.0000x reference)
//
#include <hip/hip_runtime.h>
#include <cstdint>
#include <cstddef>

// ---------------------------------------------------------------------------
// DynamicMemoryCell on MI355X (gfx950) — round 3 (round-2 plan, compile fix)
//
// Math: softmax over 1 key == 1 -> attn == v; q/k/pm dead.
// The linear chain pi->v->ctx->gi is collapsed into one GEMM with
//   Wcomb = Wih @ Wop @ Wv @ Wip   [3072,1024]  (precomputed per call)
//   bcomb = ((bip@Wv^T+bv)@Wop^T+bop)@Wih^T+bih (fp32 GEMV chain)
// Batch GEMMs: fg (K=2048) + gi_comb (N=3072) fused into ONE 2048-block
// launch; gh; og (BM=64 tile). LDS XOR-swizzle kills ds_read bank conflicts.
// ---------------------------------------------------------------------------

typedef __bf16 bf16;
typedef bf16 bf16x4 __attribute__((ext_vector_type(4)));
typedef bf16 bf16x8 __attribute__((ext_vector_type(8)));
typedef float f32x4 __attribute__((ext_vector_type(4)));

#define B_ROWS 8192

__device__ __forceinline__ float sigmoid_f(float x) {
    return 1.0f / (1.0f + __expf(-x));
}
__device__ __forceinline__ float tanh_f(float x) {
    return 1.0f - 2.0f / (__expf(2.0f * x) + 1.0f);
}

// XOR swizzle of the 16B column-chunk within a 64B LDS row. Applied to the
// GLOBAL address on the staging side (LDS slot stays base+lane*16, as
// global_load_lds requires) and to the ds_read address on the consume side
// (XOR is an involution, so the consume-side lookup recovers the chunk).
__device__ __forceinline__ int swz(int row, int cc) {
    return cc ^ (row & 3) ^ ((row >> 2) & 3);
}

// ---------------------------------------------------------------------------
// Core GEMM: C[M,N] = A[M,K] @ W[N,K]^T + bias.  Block tile BM x 128, BK=32,
// 4 waves; wave tile (BM/2) x 64 via mfma_f32_16x16x32_bf16.
// epi 0: out_bf = bf16(val)
// epi 1: out_bf = bf16(aux_f32 * sigmoid(val))        (forget gate)
// epi 2: out_f32 = float(aux_bf) * sigmoid(val)       (output gate)
// epi 3: out_bf[gcol*tld + grow] = bf16(val)          (transposed store)
// ---------------------------------------------------------------------------
template <int BM>
__device__ __forceinline__ void gemm_core(
    bf16* sA, bf16* sB,
    const bf16* __restrict__ A, int lda,
    const bf16* __restrict__ W, int ldw,
    const float* __restrict__ bias,
    int N, int K, int brow, int bcol, int epi,
    bf16* __restrict__ out_bf, float* __restrict__ out_f32,
    const float* __restrict__ aux_f32, const bf16* __restrict__ aux_bf,
    int tld)
{
    constexpr int AI = BM / 32;
    const int tid  = threadIdx.x;
    const int lane = tid & 63;
    const int wave = tid >> 6;
    const int wr   = (wave & 1) * (BM / 2);
    const int wc   = (wave >> 1) * 64;
    const int lrow = lane & 15;
    const int lq   = lane >> 4;

    f32x4 acc[AI][4];
#pragma unroll
    for (int i = 0; i < AI; ++i)
#pragma unroll
        for (int j = 0; j < 4; ++j) {
            f32x4 z = {0.0f, 0.0f, 0.0f, 0.0f};
            acc[i][j] = z;
        }

    for (int k0 = 0; k0 < K; k0 += 32) {
        // stage A tile (BM rows x 32): lane's LDS slot is fixed; fetch the
        // swizzled global chunk so consume-side reads are conflict-free.
#pragma unroll
        for (int i = 0; i < BM / 64; ++i) {
            int s   = tid + i * 256;
            int row = s >> 2;
            int cc  = swz(row, s & 3);
            const bf16* gp = A + (size_t)(brow + row) * lda + (k0 + cc * 8);
            __builtin_amdgcn_global_load_lds(
                (const __attribute__((address_space(1))) void*)gp,
                (__attribute__((address_space(3))) void*)(&sA[s * 8]),
                16, 0, 0);
        }
        // stage W tile (128 rows x 32)
#pragma unroll
        for (int i = 0; i < 2; ++i) {
            int s   = tid + i * 256;
            int row = s >> 2;
            int cc  = swz(row, s & 3);
            const bf16* gp = W + (size_t)(bcol + row) * ldw + (k0 + cc * 8);
            __builtin_amdgcn_global_load_lds(
                (const __attribute__((address_space(1))) void*)gp,
                (__attribute__((address_space(3))) void*)(&sB[s * 8]),
                16, 0, 0);
        }
        __syncthreads();

        bf16x8 av[AI], bvf[4];
#pragma unroll
        for (int i = 0; i < AI; ++i) {
            int r = wr + i * 16 + lrow;
            av[i] = *(const bf16x8*)&sA[(r * 4 + swz(r, lq)) * 8];
        }
#pragma unroll
        for (int j = 0; j < 4; ++j) {
            int r = wc + j * 16 + lrow;
            bvf[j] = *(const bf16x8*)&sB[(r * 4 + swz(r, lq)) * 8];
        }

#pragma unroll
        for (int i = 0; i < AI; ++i)
#pragma unroll
            for (int j = 0; j < 4; ++j)
                acc[i][j] = __builtin_amdgcn_mfma_f32_16x16x32_bf16(
                    av[i], bvf[j], acc[i][j], 0, 0, 0);

        __syncthreads();
    }

    // epilogue: C/D layout col = lane&15, row = (lane>>4)*4 + reg
#pragma unroll
    for (int j = 0; j < 4; ++j) {
        const int gcol = bcol + wc + j * 16 + lrow;
        const float bj = bias ? bias[gcol] : 0.0f;
#pragma unroll
        for (int i = 0; i < AI; ++i) {
            const int growb = brow + wr + i * 16 + lq * 4;
#pragma unroll
            for (int r = 0; r < 4; ++r) {
                const int grow = growb + r;
                const float val = acc[i][j][r] + bj;
                if (epi == 0) {
                    out_bf[(size_t)grow * N + gcol] = (bf16)val;
                } else if (epi == 1) {
                    const size_t idx = (size_t)grow * N + gcol;
                    out_bf[idx] = (bf16)(aux_f32[idx] * sigmoid_f(val));
                } else if (epi == 2) {
                    const size_t idx = (size_t)grow * N + gcol;
                    out_f32[idx] = (float)aux_bf[idx] * sigmoid_f(val);
                } else {
                    out_bf[(size_t)gcol * tld + grow] = (bf16)val;
                }
            }
        }
    }
}

__global__ __launch_bounds__(256, 2) void gemm128_k(
    const bf16* __restrict__ A, int lda, const bf16* __restrict__ W, int ldw,
    const float* __restrict__ bias, int N, int K, int epi,
    bf16* __restrict__ out_bf, float* __restrict__ out_f32,
    const float* __restrict__ aux_f32, const bf16* __restrict__ aux_bf, int tld)
{
    __shared__ bf16 sA[128 * 32];
    __shared__ bf16 sB[128 * 32];
    gemm_core<128>(sA, sB, A, lda, W, ldw, bias, N, K,
                   blockIdx.y * 128, blockIdx.x * 128, epi,
                   out_bf, out_f32, aux_f32, aux_bf, tld);
}

__global__ __launch_bounds__(256, 2) void gemm64_k(
    const bf16* __restrict__ A, int lda, const bf16* __restrict__ W, int ldw,
    const float* __restrict__ bias, int N, int K, int epi,
    bf16* __restrict__ out_bf, float* __restrict__ out_f32,
    const float* __restrict__ aux_f32, const bf16* __restrict__ aux_bf, int tld)
{
    __shared__ bf16 sA[64 * 32];
    __shared__ bf16 sB[128 * 32];
    gemm_core<64>(sA, sB, A, lda, W, ldw, bias, N, K,
                  blockIdx.y * 64, blockIdx.x * 128, epi,
                  out_bf, out_f32, aux_f32, aux_bf, tld);
}

// fg (x<8) + gi_comb (x>=8) in one launch: 32x64 = 2048 blocks -> 8/CU.
__global__ __launch_bounds__(256, 2) void gemm_fused_k(
    const bf16* __restrict__ CAT, const bf16* __restrict__ WFG,
    const float* __restrict__ fg_b, const float* __restrict__ prev,
    bf16* __restrict__ GATED,
    const bf16* __restrict__ WCOMB, const float* __restrict__ t3b,
    bf16* __restrict__ GI)
{
    __shared__ bf16 sA[128 * 32];
    __shared__ bf16 sB[128 * 32];
    const int brow = blockIdx.y * 128;
    if (blockIdx.x < 8) {
        gemm_core<128>(sA, sB, CAT, 2048, WFG, 2048, fg_b, 1024, 2048,
                       brow, blockIdx.x * 128, 1, GATED, nullptr, prev,
                       nullptr, 0);
    } else {
        gemm_core<128>(sA, sB, CAT + 1024, 2048, WCOMB, 1024, t3b, 3072, 1024,
                       brow, (blockIdx.x - 8) * 128, 0, GI, nullptr, nullptr,
                       nullptr, 0);
    }
}

// ---------------------------------------------------------------------------
// Elementwise / small helpers
// ---------------------------------------------------------------------------
__global__ void cast_f32_bf16_k(const float* __restrict__ src,
                                bf16* __restrict__ dst, int n4) {
    int i = blockIdx.x * 256 + threadIdx.x;
    if (i >= n4) return;
    f32x4 v = ((const f32x4*)src)[i];
    bf16x4 o = {(bf16)v[0], (bf16)v[1], (bf16)v[2], (bf16)v[3]};
    ((bf16x4*)dst)[i] = o;
}

__global__ void build_cat_k(const float* __restrict__ mem,
                            const float* __restrict__ inp,
                            bf16* __restrict__ cat) {
    int i = blockIdx.x * 256 + threadIdx.x;
    int row = i >> 9;
    int c4  = i & 511;
    f32x4 v;
    if (c4 < 256)
        v = ((const f32x4*)mem)[(size_t)row * 256 + c4];
    else
        v = ((const f32x4*)inp)[(size_t)row * 256 + (c4 - 256)];
    bf16x4 o = {(bf16)v[0], (bf16)v[1], (bf16)v[2], (bf16)v[3]};
    ((bf16x4*)cat)[i] = o;
}

// src [R,C] f32  ->  dst [C,R] bf16
__global__ void transpose_cast_k(const float* __restrict__ src,
                                 bf16* __restrict__ dst, int R, int C) {
    __shared__ float t[32][33];
    int bx = blockIdx.x * 32;  // col offset in src
    int by = blockIdx.y * 32;  // row offset in src
    int tx = threadIdx.x & 31, ty = threadIdx.x >> 5;
#pragma unroll
    for (int i = 0; i < 32; i += 8)
        t[ty + i][tx] = src[(size_t)(by + ty + i) * C + bx + tx];
    __syncthreads();
#pragma unroll
    for (int i = 0; i < 32; i += 8)
        dst[(size_t)(bx + ty + i) * R + by + tx] = (bf16)t[tx][ty + i];
}

// y[n] = b[n] + sum_k W[n,k] * x[k]   (fp32; one wave per output row)
__global__ void gemv_k(const float* __restrict__ W, const float* __restrict__ x,
                       const float* __restrict__ b, float* __restrict__ y,
                       int K) {
    int n    = blockIdx.x * 4 + (threadIdx.x >> 6);
    int lane = threadIdx.x & 63;
    const float* row = W + (size_t)n * K;
    float s = 0.0f;
    for (int k = lane * 4; k < K; k += 256) {
        f32x4 w = *(const f32x4*)(row + k);
        f32x4 xv = *(const f32x4*)(x + k);
        s += w[0] * xv[0] + w[1] * xv[1] + w[2] * xv[2] + w[3] * xv[3];
    }
#pragma unroll
    for (int off = 32; off; off >>= 1) s += __shfl_down(s, off);
    if (lane == 0) y[n] = s + b[n];
}

// GRU combine, in place: upd (=gated buffer) = (1-z)*n + z*gated
__global__ void gru_combine_k(const bf16* __restrict__ gi,
                              const bf16* __restrict__ gh,
                              bf16* __restrict__ gated) {
    int i   = blockIdx.x * 256 + threadIdx.x;
    int row = i >> 7;
    int c   = (i & 127) << 3;
    size_t b3 = (size_t)row * 3072 + c;
    size_t b1 = (size_t)row * 1024 + c;
    bf16x8 gir = *(const bf16x8*)(gi + b3);
    bf16x8 giz = *(const bf16x8*)(gi + b3 + 1024);
    bf16x8 gin = *(const bf16x8*)(gi + b3 + 2048);
    bf16x8 ghr = *(const bf16x8*)(gh + b3);
    bf16x8 ghz = *(const bf16x8*)(gh + b3 + 1024);
    bf16x8 ghn = *(const bf16x8*)(gh + b3 + 2048);
    bf16x8 g   = *(const bf16x8*)(gated + b1);
    bf16x8 o;
#pragma unroll
    for (int e = 0; e < 8; ++e) {
        float r = sigmoid_f((float)gir[e] + (float)ghr[e]);
        float z = sigmoid_f((float)giz[e] + (float)ghz[e]);
        float n = tanh_f((float)gin[e] + r * (float)ghn[e]);
        o[e] = (bf16)((1.0f - z) * n + z * (float)g[e]);
    }
    *(bf16x8*)(gated + b1) = o;
}

__global__ void fill_ones_k(float* __restrict__ p, int n) {
    int i = blockIdx.x * 256 + threadIdx.x;
    if (i < n) p[i] = 1.0f;
}

// ---------------------------------------------------------------------------
// Launch
// ---------------------------------------------------------------------------
extern "C" void kernel_launch(void* const* d_in, const int* in_sizes, int n_in,
                              void* d_out, int out_size, void* d_ws,
                              size_t ws_size, hipStream_t stream) {
    const float* input      = (const float*)d_in[0];
    const float* prev       = (const float*)d_in[1];
    const float* in_proj_w  = (const float*)d_in[2];
    const float* in_proj_b  = (const float*)d_in[3];
    const float* out_proj_w = (const float*)d_in[4];
    const float* out_proj_b = (const float*)d_in[5];
    const float* ip_w       = (const float*)d_in[6];
    const float* ip_b       = (const float*)d_in[7];
    // d_in[8]/d_in[9] (mp_w/mp_b) dead: softmax over one key == 1
    const float* fg_w  = (const float*)d_in[10];
    const float* fg_b  = (const float*)d_in[11];
    const float* og_w  = (const float*)d_in[12];
    const float* og_b  = (const float*)d_in[13];
    const float* gih_w = (const float*)d_in[14];
    const float* gih_b = (const float*)d_in[15];
    const float* ghh_w = (const float*)d_in[16];
    const float* ghh_b = (const float*)d_in[17];
    float* out = (float*)d_out;

    // ---- workspace layout (152 MiB, aggressive overlap; see timeline notes)
    char* ws = (char*)d_ws;
    const size_t MB = 1024 * 1024;
    bf16* CAT   = (bf16*)(ws);             // [0,32M)  steps 1-8, then dead
    bf16* WHHB  = (bf16*)(ws);             // 6M, cast AFTER fused gemm
    bf16* GI    = (bf16*)(ws + 32 * MB);   // [32,80M)  written step 8
    bf16* GH    = (bf16*)(ws + 80 * MB);   // [80,128M) written step 10
    // temporaries inside the GH region (all dead before GH is written):
    bf16* WVB   = (bf16*)(ws + 80 * MB);   // 2M
    bf16* WOPB  = (bf16*)(ws + 82 * MB);   // 2M
    bf16* WIHB  = (bf16*)(ws + 84 * MB);   // 6M
    bf16* WIPT  = (bf16*)(ws + 90 * MB);   // 2M
    bf16* T1T   = (bf16*)(ws + 92 * MB);   // 2M
    bf16* T2T   = (bf16*)(ws + 94 * MB);   // 2M
    bf16* WFGB  = (bf16*)(ws + 96 * MB);   // 4M (read during step 8; GH later)
    float* T1B  = (float*)(ws + 100 * MB);
    float* T2B  = (float*)(ws + 100 * MB + 8192);
    float* T3B  = (float*)(ws + 100 * MB + 16384);
    bf16* GATED = (bf16*)(ws + 128 * MB);  // [128,144M); becomes UPD in place
    bf16* WCOMB = (bf16*)(ws + 144 * MB);  // [144,150M)
    bf16* WOGB  = (bf16*)(ws + 150 * MB);  // [150,152M)

    const int M = B_ROWS;
    dim3 blk(256);

    // 1. activations -> bf16 concat
    build_cat_k<<<dim3((M * 2048 / 4) / 256), blk, 0, stream>>>(prev, input, CAT);
    // 2. weight casts (Whh deferred — its slot overlaps CAT)
    cast_f32_bf16_k<<<dim3(1024), blk, 0, stream>>>(in_proj_w + 2048 * 1024, WVB, 1024 * 1024 / 4);
    cast_f32_bf16_k<<<dim3(1024), blk, 0, stream>>>(out_proj_w, WOPB, 1024 * 1024 / 4);
    cast_f32_bf16_k<<<dim3(3072), blk, 0, stream>>>(gih_w, WIHB, 3072 * 1024 / 4);
    cast_f32_bf16_k<<<dim3(2048), blk, 0, stream>>>(fg_w, WFGB, 1024 * 2048 / 4);
    cast_f32_bf16_k<<<dim3(1024), blk, 0, stream>>>(og_w, WOGB, 1024 * 1024 / 4);
    // 3. Wip^T (bf16)
    transpose_cast_k<<<dim3(32, 32), blk, 0, stream>>>(ip_w, WIPT, 1024, 1024);
    // 4. bias chain (fp32, exact):
    gemv_k<<<dim3(256), blk, 0, stream>>>(in_proj_w + 2048 * 1024, ip_b, in_proj_b + 2048, T1B, 1024);
    gemv_k<<<dim3(256), blk, 0, stream>>>(out_proj_w, T1B, out_proj_b, T2B, 1024);
    gemv_k<<<dim3(768), blk, 0, stream>>>(gih_w, T2B, gih_b, T3B, 1024);
    // 5-7. weight composition: Wcomb = Wih @ Wop @ Wv @ Wip
    gemm64_k<<<dim3(8, 16), blk, 0, stream>>>(WVB, 1024, WIPT, 1024, nullptr,
        1024, 1024, 3, T1T, nullptr, nullptr, nullptr, 1024);   // (Wv@Wip)^T
    gemm64_k<<<dim3(8, 16), blk, 0, stream>>>(WOPB, 1024, T1T, 1024, nullptr,
        1024, 1024, 3, T2T, nullptr, nullptr, nullptr, 1024);   // (Wop@..)^T
    gemm64_k<<<dim3(8, 48), blk, 0, stream>>>(WIHB, 1024, T2T, 1024, nullptr,
        1024, 1024, 0, WCOMB, nullptr, nullptr, nullptr, 0);    // Wcomb
    // 8. fused: gated = prev*sigmoid(cat@Wfg^T+bfg); gi = x@Wcomb^T + bcomb
    gemm_fused_k<<<dim3(32, M / 128), blk, 0, stream>>>(CAT, WFGB, fg_b, prev,
                                                        GATED, WCOMB, T3B, GI);
    // 9. Whh cast (CAT now dead)
    cast_f32_bf16_k<<<dim3(3072), blk, 0, stream>>>(ghh_w, WHHB, 3072 * 1024 / 4);
    // 10. gh = gated @ Whh^T + bhh
    gemm128_k<<<dim3(24, M / 128), blk, 0, stream>>>(GATED, 1024, WHHB, 1024,
        ghh_b, 3072, 1024, 0, GH, nullptr, nullptr, nullptr, 0);
    // 11. GRU combine (in place: GATED becomes UPD)
    gru_combine_k<<<dim3(M * 1024 / 8 / 256), blk, 0, stream>>>(GI, GH, GATED);
    // 12. out = upd * sigmoid(upd @ Wog^T + bog)
    gemm64_k<<<dim3(8, M / 64), blk, 0, stream>>>(GATED, 1024, WOGB, 1024,
        og_b, 1024, 1024, 2, nullptr, out, nullptr, GATED, 0);
    // 13. attention weights == 1.0
    fill_ones_k<<<dim3(32), blk, 0, stream>>>(out + (size_t)M * 1024, M);
}

// Round 4
// 572.626 us; speedup vs baseline: 1.0359x; 1.0359x over previous
//
#include <hip/hip_runtime.h>
#include <cstdint>
#include <cstddef>

// ---------------------------------------------------------------------------
// DynamicMemoryCell on MI355X (gfx950) — round 4
//
// Math: softmax over 1 key == 1 -> attn == v; q/k/pm dead.
// Linear chain pi->v->ctx->gi collapsed: Wcomb = Wih@Wop@Wv@Wip (per call).
// Round-4 changes vs round-3:
//   * fusion REVERTED (measured +45 us), swizzle REVERTED (measured no-op on
//     SQ_LDS_BANK_CONFLICT: fused 1.049e7 == round-1 fg+gi sum exactly)
//   * K-pipeline: double-buffered LDS, prefetch next tiles BEFORE the wait,
//     raw `s_waitcnt vmcnt(N); s_barrier` instead of __syncthreads so the
//     prefetch stays in flight across the barrier (the compiler's vmcnt(0)
//     drain before s_barrier was the ~exposed-latency stall at 2 blocks/CU).
//   * og GEMM at BM=128 (staging 384->256 MB).
// ---------------------------------------------------------------------------

typedef __bf16 bf16;
typedef bf16 bf16x4 __attribute__((ext_vector_type(4)));
typedef bf16 bf16x8 __attribute__((ext_vector_type(8)));
typedef float f32x4 __attribute__((ext_vector_type(4)));

#define B_ROWS 8192

__device__ __forceinline__ float sigmoid_f(float x) {
    return 1.0f / (1.0f + __expf(-x));
}
__device__ __forceinline__ float tanh_f(float x) {
    return 1.0f - 2.0f / (__expf(2.0f * x) + 1.0f);
}

// ---------------------------------------------------------------------------
// Core GEMM: C[M,N] = A[M,K] @ W[N,K]^T + bias.  Block tile BM x 128, BK=32,
// 4 waves; wave tile (BM/2) x 64 via mfma_f32_16x16x32_bf16.
// Double-buffered K-pipeline with raw vmcnt/barrier (see header comment).
// epi 0: out_bf = bf16(val)
// epi 1: out_bf = bf16(aux_f32 * sigmoid(val))        (forget gate)
// epi 2: out_f32 = float(aux_bf) * sigmoid(val)       (output gate)
// epi 3: out_bf[gcol*tld + grow] = bf16(val)          (transposed store)
// ---------------------------------------------------------------------------
template <int BM>
__device__ __forceinline__ void gemm_core(
    bf16* sA0, bf16* sA1, bf16* sB0, bf16* sB1,
    const bf16* __restrict__ A, int lda,
    const bf16* __restrict__ W, int ldw,
    const float* __restrict__ bias,
    int N, int K, int brow, int bcol, int epi,
    bf16* __restrict__ out_bf, float* __restrict__ out_f32,
    const float* __restrict__ aux_f32, const bf16* __restrict__ aux_bf,
    int tld)
{
    constexpr int AI  = BM / 32;   // MFMA row-tiles per wave
    constexpr int ANL = BM / 64;   // A 16B-chunks per thread per stage
    const int tid  = threadIdx.x;
    const int lane = tid & 63;
    const int wave = tid >> 6;
    const int wr   = (wave & 1) * (BM / 2);
    const int wc   = (wave >> 1) * 64;
    const int lrow = lane & 15;
    const int lq   = lane >> 4;

    // stage tiles for k0 into buffer `buf` (ANL+2 global_load_lds per thread)
    auto stage = [&](int buf, int k0) {
        bf16* dA = buf ? sA1 : sA0;
        bf16* dB = buf ? sB1 : sB0;
#pragma unroll
        for (int i = 0; i < ANL; ++i) {
            int s = tid + i * 256;
            int row = s >> 2, col = (s & 3) << 3;
            const bf16* gp = A + (size_t)(brow + row) * lda + (k0 + col);
            __builtin_amdgcn_global_load_lds(
                (const __attribute__((address_space(1))) void*)gp,
                (__attribute__((address_space(3))) void*)(&dA[s * 8]),
                16, 0, 0);
        }
#pragma unroll
        for (int i = 0; i < 2; ++i) {
            int s = tid + i * 256;
            int row = s >> 2, col = (s & 3) << 3;
            const bf16* gp = W + (size_t)(bcol + row) * ldw + (k0 + col);
            __builtin_amdgcn_global_load_lds(
                (const __attribute__((address_space(1))) void*)gp,
                (__attribute__((address_space(3))) void*)(&dB[s * 8]),
                16, 0, 0);
        }
    };

    f32x4 acc[AI][4];
#pragma unroll
    for (int i = 0; i < AI; ++i)
#pragma unroll
        for (int j = 0; j < 4; ++j) {
            f32x4 z = {0.0f, 0.0f, 0.0f, 0.0f};
            acc[i][j] = z;
        }

    stage(0, 0);
    int p = 0;
    for (int k0 = 0; k0 < K; k0 += 32) {
        const bool pf = (k0 + 32 < K);
        if (pf) {
            stage(p ^ 1, k0 + 32);
            // Wait for the CURRENT buffer's loads only (the ANL+2 newest are
            // the prefetch; keep them in flight across the barrier).
            if constexpr (ANL + 2 == 4)
                asm volatile("s_waitcnt vmcnt(4)\n\ts_barrier" ::: "memory");
            else
                asm volatile("s_waitcnt vmcnt(3)\n\ts_barrier" ::: "memory");
        } else {
            asm volatile("s_waitcnt vmcnt(0)\n\ts_barrier" ::: "memory");
        }

        const bf16* cA = p ? sA1 : sA0;
        const bf16* cB = p ? sB1 : sB0;
        bf16x8 av[AI], bvf[4];
#pragma unroll
        for (int i = 0; i < AI; ++i)
            av[i] = *(const bf16x8*)&cA[(wr + i * 16 + lrow) * 32 + lq * 8];
#pragma unroll
        for (int j = 0; j < 4; ++j)
            bvf[j] = *(const bf16x8*)&cB[(wc + j * 16 + lrow) * 32 + lq * 8];
        // All waves must COMPLETE their ds_reads of buf p before any wave's
        // next-iter stage() overwrites it.
        asm volatile("s_waitcnt lgkmcnt(0)\n\ts_barrier" ::: "memory");

#pragma unroll
        for (int i = 0; i < AI; ++i)
#pragma unroll
            for (int j = 0; j < 4; ++j)
                acc[i][j] = __builtin_amdgcn_mfma_f32_16x16x32_bf16(
                    av[i], bvf[j], acc[i][j], 0, 0, 0);

        p ^= 1;
    }

    // epilogue: C/D layout col = lane&15, row = (lane>>4)*4 + reg
#pragma unroll
    for (int j = 0; j < 4; ++j) {
        const int gcol = bcol + wc + j * 16 + lrow;
        const float bj = bias ? bias[gcol] : 0.0f;
#pragma unroll
        for (int i = 0; i < AI; ++i) {
            const int growb = brow + wr + i * 16 + lq * 4;
#pragma unroll
            for (int r = 0; r < 4; ++r) {
                const int grow = growb + r;
                const float val = acc[i][j][r] + bj;
                if (epi == 0) {
                    out_bf[(size_t)grow * N + gcol] = (bf16)val;
                } else if (epi == 1) {
                    const size_t idx = (size_t)grow * N + gcol;
                    out_bf[idx] = (bf16)(aux_f32[idx] * sigmoid_f(val));
                } else if (epi == 2) {
                    const size_t idx = (size_t)grow * N + gcol;
                    out_f32[idx] = (float)aux_bf[idx] * sigmoid_f(val);
                } else {
                    out_bf[(size_t)gcol * tld + grow] = (bf16)val;
                }
            }
        }
    }
}

__global__ __launch_bounds__(256, 2) void gemm128_k(
    const bf16* __restrict__ A, int lda, const bf16* __restrict__ W, int ldw,
    const float* __restrict__ bias, int N, int K, int epi,
    bf16* __restrict__ out_bf, float* __restrict__ out_f32,
    const float* __restrict__ aux_f32, const bf16* __restrict__ aux_bf, int tld)
{
    __shared__ bf16 sA[2][128 * 32];
    __shared__ bf16 sB[2][128 * 32];
    gemm_core<128>(sA[0], sA[1], sB[0], sB[1], A, lda, W, ldw, bias, N, K,
                   blockIdx.y * 128, blockIdx.x * 128, epi,
                   out_bf, out_f32, aux_f32, aux_bf, tld);
}

__global__ __launch_bounds__(256, 2) void gemm64_k(
    const bf16* __restrict__ A, int lda, const bf16* __restrict__ W, int ldw,
    const float* __restrict__ bias, int N, int K, int epi,
    bf16* __restrict__ out_bf, float* __restrict__ out_f32,
    const float* __restrict__ aux_f32, const bf16* __restrict__ aux_bf, int tld)
{
    __shared__ bf16 sA[2][64 * 32];
    __shared__ bf16 sB[2][128 * 32];
    gemm_core<64>(sA[0], sA[1], sB[0], sB[1], A, lda, W, ldw, bias, N, K,
                  blockIdx.y * 64, blockIdx.x * 128, epi,
                  out_bf, out_f32, aux_f32, aux_bf, tld);
}

// ---------------------------------------------------------------------------
// Elementwise / small helpers
// ---------------------------------------------------------------------------
__global__ void cast_f32_bf16_k(const float* __restrict__ src,
                                bf16* __restrict__ dst, int n4) {
    int i = blockIdx.x * 256 + threadIdx.x;
    if (i >= n4) return;
    f32x4 v = ((const f32x4*)src)[i];
    bf16x4 o = {(bf16)v[0], (bf16)v[1], (bf16)v[2], (bf16)v[3]};
    ((bf16x4*)dst)[i] = o;
}

__global__ void build_cat_k(const float* __restrict__ mem,
                            const float* __restrict__ inp,
                            bf16* __restrict__ cat) {
    int i = blockIdx.x * 256 + threadIdx.x;
    int row = i >> 9;
    int c4  = i & 511;
    f32x4 v;
    if (c4 < 256)
        v = ((const f32x4*)mem)[(size_t)row * 256 + c4];
    else
        v = ((const f32x4*)inp)[(size_t)row * 256 + (c4 - 256)];
    bf16x4 o = {(bf16)v[0], (bf16)v[1], (bf16)v[2], (bf16)v[3]};
    ((bf16x4*)cat)[i] = o;
}

// src [R,C] f32  ->  dst [C,R] bf16
__global__ void transpose_cast_k(const float* __restrict__ src,
                                 bf16* __restrict__ dst, int R, int C) {
    __shared__ float t[32][33];
    int bx = blockIdx.x * 32;
    int by = blockIdx.y * 32;
    int tx = threadIdx.x & 31, ty = threadIdx.x >> 5;
#pragma unroll
    for (int i = 0; i < 32; i += 8)
        t[ty + i][tx] = src[(size_t)(by + ty + i) * C + bx + tx];
    __syncthreads();
#pragma unroll
    for (int i = 0; i < 32; i += 8)
        dst[(size_t)(bx + ty + i) * R + by + tx] = (bf16)t[tx][ty + i];
}

// y[n] = b[n] + sum_k W[n,k] * x[k]   (fp32; one wave per output row)
__global__ void gemv_k(const float* __restrict__ W, const float* __restrict__ x,
                       const float* __restrict__ b, float* __restrict__ y,
                       int K) {
    int n    = blockIdx.x * 4 + (threadIdx.x >> 6);
    int lane = threadIdx.x & 63;
    const float* row = W + (size_t)n * K;
    float s = 0.0f;
    for (int k = lane * 4; k < K; k += 256) {
        f32x4 w = *(const f32x4*)(row + k);
        f32x4 xv = *(const f32x4*)(x + k);
        s += w[0] * xv[0] + w[1] * xv[1] + w[2] * xv[2] + w[3] * xv[3];
    }
#pragma unroll
    for (int off = 32; off; off >>= 1) s += __shfl_down(s, off);
    if (lane == 0) y[n] = s + b[n];
}

// GRU combine, in place: upd (=gated buffer) = (1-z)*n + z*gated
__global__ void gru_combine_k(const bf16* __restrict__ gi,
                              const bf16* __restrict__ gh,
                              bf16* __restrict__ gated) {
    int i   = blockIdx.x * 256 + threadIdx.x;
    int row = i >> 7;
    int c   = (i & 127) << 3;
    size_t b3 = (size_t)row * 3072 + c;
    size_t b1 = (size_t)row * 1024 + c;
    bf16x8 gir = *(const bf16x8*)(gi + b3);
    bf16x8 giz = *(const bf16x8*)(gi + b3 + 1024);
    bf16x8 gin = *(const bf16x8*)(gi + b3 + 2048);
    bf16x8 ghr = *(const bf16x8*)(gh + b3);
    bf16x8 ghz = *(const bf16x8*)(gh + b3 + 1024);
    bf16x8 ghn = *(const bf16x8*)(gh + b3 + 2048);
    bf16x8 g   = *(const bf16x8*)(gated + b1);
    bf16x8 o;
#pragma unroll
    for (int e = 0; e < 8; ++e) {
        float r = sigmoid_f((float)gir[e] + (float)ghr[e]);
        float z = sigmoid_f((float)giz[e] + (float)ghz[e]);
        float n = tanh_f((float)gin[e] + r * (float)ghn[e]);
        o[e] = (bf16)((1.0f - z) * n + z * (float)g[e]);
    }
    *(bf16x8*)(gated + b1) = o;
}

__global__ void fill_ones_k(float* __restrict__ p, int n) {
    int i = blockIdx.x * 256 + threadIdx.x;
    if (i < n) p[i] = 1.0f;
}

// ---------------------------------------------------------------------------
// Launch
// ---------------------------------------------------------------------------
extern "C" void kernel_launch(void* const* d_in, const int* in_sizes, int n_in,
                              void* d_out, int out_size, void* d_ws,
                              size_t ws_size, hipStream_t stream) {
    const float* input      = (const float*)d_in[0];
    const float* prev       = (const float*)d_in[1];
    const float* in_proj_w  = (const float*)d_in[2];
    const float* in_proj_b  = (const float*)d_in[3];
    const float* out_proj_w = (const float*)d_in[4];
    const float* out_proj_b = (const float*)d_in[5];
    const float* ip_w       = (const float*)d_in[6];
    const float* ip_b       = (const float*)d_in[7];
    // d_in[8]/d_in[9] (mp_w/mp_b) dead: softmax over one key == 1
    const float* fg_w  = (const float*)d_in[10];
    const float* fg_b  = (const float*)d_in[11];
    const float* og_w  = (const float*)d_in[12];
    const float* og_b  = (const float*)d_in[13];
    const float* gih_w = (const float*)d_in[14];
    const float* gih_b = (const float*)d_in[15];
    const float* ghh_w = (const float*)d_in[16];
    const float* ghh_b = (const float*)d_in[17];
    float* out = (float*)d_out;

    // ---- workspace layout (152 MiB, overlaps respect dependency order)
    char* ws = (char*)d_ws;
    const size_t MB = 1024 * 1024;
    bf16* CAT   = (bf16*)(ws);             // [0,32M)  live until gi done
    bf16* WHHB  = (bf16*)(ws);             // 6M, cast AFTER gi (overlaps CAT)
    bf16* GI    = (bf16*)(ws + 32 * MB);   // [32,80M)
    bf16* GH    = (bf16*)(ws + 80 * MB);   // [80,128M) written late
    // temporaries inside the GH region (dead before GH is written):
    bf16* WVB   = (bf16*)(ws + 80 * MB);   // 2M
    bf16* WOPB  = (bf16*)(ws + 82 * MB);   // 2M
    bf16* WIHB  = (bf16*)(ws + 84 * MB);   // 6M
    bf16* WIPT  = (bf16*)(ws + 90 * MB);   // 2M
    bf16* T1T   = (bf16*)(ws + 92 * MB);   // 2M
    bf16* T2T   = (bf16*)(ws + 94 * MB);   // 2M
    bf16* WFGB  = (bf16*)(ws + 96 * MB);   // 4M
    float* T1B  = (float*)(ws + 100 * MB);
    float* T2B  = (float*)(ws + 100 * MB + 8192);
    float* T3B  = (float*)(ws + 100 * MB + 16384);
    bf16* GATED = (bf16*)(ws + 128 * MB);  // [128,144M); becomes UPD in place
    bf16* WCOMB = (bf16*)(ws + 144 * MB);  // [144,150M)
    bf16* WOGB  = (bf16*)(ws + 150 * MB);  // [150,152M)

    const int M = B_ROWS;
    dim3 blk(256);

    // 1. activations -> bf16 concat
    build_cat_k<<<dim3((M * 2048 / 4) / 256), blk, 0, stream>>>(prev, input, CAT);
    // 2. weight casts (Whh deferred — its slot overlaps CAT)
    cast_f32_bf16_k<<<dim3(1024), blk, 0, stream>>>(in_proj_w + 2048 * 1024, WVB, 1024 * 1024 / 4);
    cast_f32_bf16_k<<<dim3(1024), blk, 0, stream>>>(out_proj_w, WOPB, 1024 * 1024 / 4);
    cast_f32_bf16_k<<<dim3(3072), blk, 0, stream>>>(gih_w, WIHB, 3072 * 1024 / 4);
    cast_f32_bf16_k<<<dim3(2048), blk, 0, stream>>>(fg_w, WFGB, 1024 * 2048 / 4);
    cast_f32_bf16_k<<<dim3(1024), blk, 0, stream>>>(og_w, WOGB, 1024 * 1024 / 4);
    // 3. Wip^T (bf16)
    transpose_cast_k<<<dim3(32, 32), blk, 0, stream>>>(ip_w, WIPT, 1024, 1024);
    // 4. bias chain (fp32, exact)
    gemv_k<<<dim3(256), blk, 0, stream>>>(in_proj_w + 2048 * 1024, ip_b, in_proj_b + 2048, T1B, 1024);
    gemv_k<<<dim3(256), blk, 0, stream>>>(out_proj_w, T1B, out_proj_b, T2B, 1024);
    gemv_k<<<dim3(768), blk, 0, stream>>>(gih_w, T2B, gih_b, T3B, 1024);
    // 5-7. weight composition: Wcomb = Wih @ Wop @ Wv @ Wip
    gemm64_k<<<dim3(8, 16), blk, 0, stream>>>(WVB, 1024, WIPT, 1024, nullptr,
        1024, 1024, 3, T1T, nullptr, nullptr, nullptr, 1024);   // (Wv@Wip)^T
    gemm64_k<<<dim3(8, 16), blk, 0, stream>>>(WOPB, 1024, T1T, 1024, nullptr,
        1024, 1024, 3, T2T, nullptr, nullptr, nullptr, 1024);   // (Wop@..)^T
    gemm64_k<<<dim3(8, 48), blk, 0, stream>>>(WIHB, 1024, T2T, 1024, nullptr,
        1024, 1024, 0, WCOMB, nullptr, nullptr, nullptr, 0);    // Wcomb
    // 8. gated = prev * sigmoid(cat @ Wfg^T + bfg)
    gemm128_k<<<dim3(8, M / 128), blk, 0, stream>>>(CAT, 2048, WFGB, 2048,
        fg_b, 1024, 2048, 1, GATED, nullptr, prev, nullptr, 0);
    // 9. gi = x @ Wcomb^T + bcomb
    gemm128_k<<<dim3(24, M / 128), blk, 0, stream>>>(CAT + 1024, 2048, WCOMB,
        1024, T3B, 3072, 1024, 0, GI, nullptr, nullptr, nullptr, 0);
    // 10. Whh cast (CAT now dead)
    cast_f32_bf16_k<<<dim3(3072), blk, 0, stream>>>(ghh_w, WHHB, 3072 * 1024 / 4);
    // 11. gh = gated @ Whh^T + bhh
    gemm128_k<<<dim3(24, M / 128), blk, 0, stream>>>(GATED, 1024, WHHB, 1024,
        ghh_b, 3072, 1024, 0, GH, nullptr, nullptr, nullptr, 0);
    // 12. GRU combine (in place: GATED becomes UPD)
    gru_combine_k<<<dim3(M * 1024 / 8 / 256), blk, 0, stream>>>(GI, GH, GATED);
    // 13. out = upd * sigmoid(upd @ Wog^T + bog)
    gemm128_k<<<dim3(8, M / 128), blk, 0, stream>>>(GATED, 1024, WOGB, 1024,
        og_b, 1024, 1024, 2, nullptr, out, nullptr, GATED, 0);
    // 14. attention weights == 1.0
    fill_ones_k<<<dim3(32), blk, 0, stream>>>(out + (size_t)M * 1024, M);
}

// Round 5
// 545.467 us; speedup vs baseline: 1.0874x; 1.0498x over previous
//
#include <hip/hip_runtime.h>
#include <cstdint>
#include <cstddef>

// ---------------------------------------------------------------------------
// DynamicMemoryCell on MI355X (gfx950) — round 5
//
// Math: softmax over 1 key == 1 -> attn == v; q/k/pm dead.
// Linear chain pi->v->ctx->gi collapsed: Wcomb = Wih@Wop@Wv@Wip (per call).
//
// Round-5 vs round-4:
//   * dbuf/raw-vmcnt pipeline REVERTED (measured 76->100 us on gi/gh: the
//     asm "memory" barriers pin scheduling, m141-style regression).
//   * 1-D grid with y-fastest block decode: co-resident blocks share A
//     row-tiles through L3 instead of racing 8 XCDs' L2 misses to HBM
//     (round-1 fg: FETCH 166 MB vs 36 MB unique footprint).
//   * single fused weight-cast kernel (5 launches -> 1).
// ---------------------------------------------------------------------------

typedef __bf16 bf16;
typedef bf16 bf16x4 __attribute__((ext_vector_type(4)));
typedef bf16 bf16x8 __attribute__((ext_vector_type(8)));
typedef float f32x4 __attribute__((ext_vector_type(4)));

#define B_ROWS 8192

__device__ __forceinline__ float sigmoid_f(float x) {
    return 1.0f / (1.0f + __expf(-x));
}
__device__ __forceinline__ float tanh_f(float x) {
    return 1.0f - 2.0f / (__expf(2.0f * x) + 1.0f);
}

// ---------------------------------------------------------------------------
// Core GEMM: C[M,N] = A[M,K] @ W[N,K]^T + bias.  Block tile BM x 128, BK=32,
// 4 waves; wave tile (BM/2) x 64 via mfma_f32_16x16x32_bf16. Single-buffered
// m97 structure (global_load_lds width=16; compiler-scheduled waitcnts).
// epi 0: out_bf = bf16(val)
// epi 1: out_bf = bf16(aux_f32 * sigmoid(val))        (forget gate)
// epi 2: out_f32 = float(aux_bf) * sigmoid(val)       (output gate)
// epi 3: out_bf[gcol*tld + grow] = bf16(val)          (transposed store)
// ---------------------------------------------------------------------------
template <int BM>
__device__ __forceinline__ void gemm_core(
    bf16* sA, bf16* sB,
    const bf16* __restrict__ A, int lda,
    const bf16* __restrict__ W, int ldw,
    const float* __restrict__ bias,
    int N, int K, int brow, int bcol, int epi,
    bf16* __restrict__ out_bf, float* __restrict__ out_f32,
    const float* __restrict__ aux_f32, const bf16* __restrict__ aux_bf,
    int tld)
{
    constexpr int AI = BM / 32;
    const int tid  = threadIdx.x;
    const int lane = tid & 63;
    const int wave = tid >> 6;
    const int wr   = (wave & 1) * (BM / 2);
    const int wc   = (wave >> 1) * 64;
    const int lrow = lane & 15;
    const int lq   = lane >> 4;

    f32x4 acc[AI][4];
#pragma unroll
    for (int i = 0; i < AI; ++i)
#pragma unroll
        for (int j = 0; j < 4; ++j) {
            f32x4 z = {0.0f, 0.0f, 0.0f, 0.0f};
            acc[i][j] = z;
        }

    for (int k0 = 0; k0 < K; k0 += 32) {
#pragma unroll
        for (int i = 0; i < BM / 64; ++i) {
            int s = tid + i * 256;
            int row = s >> 2, col = (s & 3) << 3;
            const bf16* gp = A + (size_t)(brow + row) * lda + (k0 + col);
            __builtin_amdgcn_global_load_lds(
                (const __attribute__((address_space(1))) void*)gp,
                (__attribute__((address_space(3))) void*)(&sA[s * 8]),
                16, 0, 0);
        }
#pragma unroll
        for (int i = 0; i < 2; ++i) {
            int s = tid + i * 256;
            int row = s >> 2, col = (s & 3) << 3;
            const bf16* gp = W + (size_t)(bcol + row) * ldw + (k0 + col);
            __builtin_amdgcn_global_load_lds(
                (const __attribute__((address_space(1))) void*)gp,
                (__attribute__((address_space(3))) void*)(&sB[s * 8]),
                16, 0, 0);
        }
        __syncthreads();

        bf16x8 av[AI], bvf[4];
#pragma unroll
        for (int i = 0; i < AI; ++i)
            av[i] = *(const bf16x8*)&sA[(wr + i * 16 + lrow) * 32 + lq * 8];
#pragma unroll
        for (int j = 0; j < 4; ++j)
            bvf[j] = *(const bf16x8*)&sB[(wc + j * 16 + lrow) * 32 + lq * 8];

#pragma unroll
        for (int i = 0; i < AI; ++i)
#pragma unroll
            for (int j = 0; j < 4; ++j)
                acc[i][j] = __builtin_amdgcn_mfma_f32_16x16x32_bf16(
                    av[i], bvf[j], acc[i][j], 0, 0, 0);

        __syncthreads();
    }

    // epilogue: C/D layout col = lane&15, row = (lane>>4)*4 + reg
#pragma unroll
    for (int j = 0; j < 4; ++j) {
        const int gcol = bcol + wc + j * 16 + lrow;
        const float bj = bias ? bias[gcol] : 0.0f;
#pragma unroll
        for (int i = 0; i < AI; ++i) {
            const int growb = brow + wr + i * 16 + lq * 4;
#pragma unroll
            for (int r = 0; r < 4; ++r) {
                const int grow = growb + r;
                const float val = acc[i][j][r] + bj;
                if (epi == 0) {
                    out_bf[(size_t)grow * N + gcol] = (bf16)val;
                } else if (epi == 1) {
                    const size_t idx = (size_t)grow * N + gcol;
                    out_bf[idx] = (bf16)(aux_f32[idx] * sigmoid_f(val));
                } else if (epi == 2) {
                    const size_t idx = (size_t)grow * N + gcol;
                    out_f32[idx] = (float)aux_bf[idx] * sigmoid_f(val);
                } else {
                    out_bf[(size_t)gcol * tld + grow] = (bf16)val;
                }
            }
        }
    }
}

// 1-D grid, y-fastest decode: by = id % nby, bx = id / nby. Co-resident
// blocks then share A row-tiles (same bx phase) -> L3 absorbs the re-reads.
__global__ __launch_bounds__(256, 2) void gemm128_k(
    const bf16* __restrict__ A, int lda, const bf16* __restrict__ W, int ldw,
    const float* __restrict__ bias, int N, int K, int epi,
    bf16* __restrict__ out_bf, float* __restrict__ out_f32,
    const float* __restrict__ aux_f32, const bf16* __restrict__ aux_bf,
    int tld, int nby)
{
    __shared__ bf16 sA[128 * 32];
    __shared__ bf16 sB[128 * 32];
    const int by = blockIdx.x % nby;
    const int bx = blockIdx.x / nby;
    gemm_core<128>(sA, sB, A, lda, W, ldw, bias, N, K,
                   by * 128, bx * 128, epi,
                   out_bf, out_f32, aux_f32, aux_bf, tld);
}

__global__ __launch_bounds__(256, 2) void gemm64_k(
    const bf16* __restrict__ A, int lda, const bf16* __restrict__ W, int ldw,
    const float* __restrict__ bias, int N, int K, int epi,
    bf16* __restrict__ out_bf, float* __restrict__ out_f32,
    const float* __restrict__ aux_f32, const bf16* __restrict__ aux_bf,
    int tld, int nby)
{
    __shared__ bf16 sA[64 * 32];
    __shared__ bf16 sB[128 * 32];
    const int by = blockIdx.x % nby;
    const int bx = blockIdx.x / nby;
    gemm_core<64>(sA, sB, A, lda, W, ldw, bias, N, K,
                  by * 64, bx * 128, epi,
                  out_bf, out_f32, aux_f32, aux_bf, tld);
}

// ---------------------------------------------------------------------------
// Elementwise / small helpers
// ---------------------------------------------------------------------------

// One launch casting all 5 front weights. Chunk = 4 floats. Segment table
// hardcoded for this problem's sizes.
__global__ void cast_weights_k(
    const float* __restrict__ wv, const float* __restrict__ wop,
    const float* __restrict__ wih, const float* __restrict__ wfg,
    const float* __restrict__ wog,
    bf16* __restrict__ dv, bf16* __restrict__ dop, bf16* __restrict__ dih,
    bf16* __restrict__ dfg, bf16* __restrict__ dog)
{
    int c = blockIdx.x * 256 + threadIdx.x;  // [0, 2097152)
    const float* s;
    bf16* d;
    int o;
    if (c < 262144)        { s = wv;  d = dv;  o = c; }
    else if (c < 524288)   { s = wop; d = dop; o = c - 262144; }
    else if (c < 1310720)  { s = wih; d = dih; o = c - 524288; }
    else if (c < 1835008)  { s = wfg; d = dfg; o = c - 1310720; }
    else                   { s = wog; d = dog; o = c - 1835008; }
    f32x4 v = ((const f32x4*)s)[o];
    bf16x4 t = {(bf16)v[0], (bf16)v[1], (bf16)v[2], (bf16)v[3]};
    ((bf16x4*)d)[o] = t;
}

__global__ void cast_f32_bf16_k(const float* __restrict__ src,
                                bf16* __restrict__ dst, int n4) {
    int i = blockIdx.x * 256 + threadIdx.x;
    if (i >= n4) return;
    f32x4 v = ((const f32x4*)src)[i];
    bf16x4 o = {(bf16)v[0], (bf16)v[1], (bf16)v[2], (bf16)v[3]};
    ((bf16x4*)dst)[i] = o;
}

__global__ void build_cat_k(const float* __restrict__ mem,
                            const float* __restrict__ inp,
                            bf16* __restrict__ cat) {
    int i = blockIdx.x * 256 + threadIdx.x;
    int row = i >> 9;
    int c4  = i & 511;
    f32x4 v;
    if (c4 < 256)
        v = ((const f32x4*)mem)[(size_t)row * 256 + c4];
    else
        v = ((const f32x4*)inp)[(size_t)row * 256 + (c4 - 256)];
    bf16x4 o = {(bf16)v[0], (bf16)v[1], (bf16)v[2], (bf16)v[3]};
    ((bf16x4*)cat)[i] = o;
}

// src [R,C] f32  ->  dst [C,R] bf16
__global__ void transpose_cast_k(const float* __restrict__ src,
                                 bf16* __restrict__ dst, int R, int C) {
    __shared__ float t[32][33];
    int bx = blockIdx.x * 32;
    int by = blockIdx.y * 32;
    int tx = threadIdx.x & 31, ty = threadIdx.x >> 5;
#pragma unroll
    for (int i = 0; i < 32; i += 8)
        t[ty + i][tx] = src[(size_t)(by + ty + i) * C + bx + tx];
    __syncthreads();
#pragma unroll
    for (int i = 0; i < 32; i += 8)
        dst[(size_t)(bx + ty + i) * R + by + tx] = (bf16)t[tx][ty + i];
}

// y[n] = b[n] + sum_k W[n,k] * x[k]   (fp32; one wave per output row)
__global__ void gemv_k(const float* __restrict__ W, const float* __restrict__ x,
                       const float* __restrict__ b, float* __restrict__ y,
                       int K) {
    int n    = blockIdx.x * 4 + (threadIdx.x >> 6);
    int lane = threadIdx.x & 63;
    const float* row = W + (size_t)n * K;
    float s = 0.0f;
    for (int k = lane * 4; k < K; k += 256) {
        f32x4 w = *(const f32x4*)(row + k);
        f32x4 xv = *(const f32x4*)(x + k);
        s += w[0] * xv[0] + w[1] * xv[1] + w[2] * xv[2] + w[3] * xv[3];
    }
#pragma unroll
    for (int off = 32; off; off >>= 1) s += __shfl_down(s, off);
    if (lane == 0) y[n] = s + b[n];
}

// GRU combine, in place: upd (=gated buffer) = (1-z)*n + z*gated
__global__ void gru_combine_k(const bf16* __restrict__ gi,
                              const bf16* __restrict__ gh,
                              bf16* __restrict__ gated) {
    int i   = blockIdx.x * 256 + threadIdx.x;
    int row = i >> 7;
    int c   = (i & 127) << 3;
    size_t b3 = (size_t)row * 3072 + c;
    size_t b1 = (size_t)row * 1024 + c;
    bf16x8 gir = *(const bf16x8*)(gi + b3);
    bf16x8 giz = *(const bf16x8*)(gi + b3 + 1024);
    bf16x8 gin = *(const bf16x8*)(gi + b3 + 2048);
    bf16x8 ghr = *(const bf16x8*)(gh + b3);
    bf16x8 ghz = *(const bf16x8*)(gh + b3 + 1024);
    bf16x8 ghn = *(const bf16x8*)(gh + b3 + 2048);
    bf16x8 g   = *(const bf16x8*)(gated + b1);
    bf16x8 o;
#pragma unroll
    for (int e = 0; e < 8; ++e) {
        float r = sigmoid_f((float)gir[e] + (float)ghr[e]);
        float z = sigmoid_f((float)giz[e] + (float)ghz[e]);
        float n = tanh_f((float)gin[e] + r * (float)ghn[e]);
        o[e] = (bf16)((1.0f - z) * n + z * (float)g[e]);
    }
    *(bf16x8*)(gated + b1) = o;
}

__global__ void fill_ones_k(float* __restrict__ p, int n) {
    int i = blockIdx.x * 256 + threadIdx.x;
    if (i < n) p[i] = 1.0f;
}

// ---------------------------------------------------------------------------
// Launch
// ---------------------------------------------------------------------------
extern "C" void kernel_launch(void* const* d_in, const int* in_sizes, int n_in,
                              void* d_out, int out_size, void* d_ws,
                              size_t ws_size, hipStream_t stream) {
    const float* input      = (const float*)d_in[0];
    const float* prev       = (const float*)d_in[1];
    const float* in_proj_w  = (const float*)d_in[2];
    const float* in_proj_b  = (const float*)d_in[3];
    const float* out_proj_w = (const float*)d_in[4];
    const float* out_proj_b = (const float*)d_in[5];
    const float* ip_w       = (const float*)d_in[6];
    const float* ip_b       = (const float*)d_in[7];
    // d_in[8]/d_in[9] (mp_w/mp_b) dead: softmax over one key == 1
    const float* fg_w  = (const float*)d_in[10];
    const float* fg_b  = (const float*)d_in[11];
    const float* og_w  = (const float*)d_in[12];
    const float* og_b  = (const float*)d_in[13];
    const float* gih_w = (const float*)d_in[14];
    const float* gih_b = (const float*)d_in[15];
    const float* ghh_w = (const float*)d_in[16];
    const float* ghh_b = (const float*)d_in[17];
    float* out = (float*)d_out;

    // ---- workspace layout (152 MiB, overlaps respect dependency order)
    char* ws = (char*)d_ws;
    const size_t MB = 1024 * 1024;
    bf16* CAT   = (bf16*)(ws);             // [0,32M)  live until gi done
    bf16* WHHB  = (bf16*)(ws);             // 6M, cast AFTER gi (overlaps CAT)
    bf16* GI    = (bf16*)(ws + 32 * MB);   // [32,80M)
    bf16* GH    = (bf16*)(ws + 80 * MB);   // [80,128M) written late
    // temporaries inside the GH region (dead before GH is written):
    bf16* WVB   = (bf16*)(ws + 80 * MB);   // 2M
    bf16* WOPB  = (bf16*)(ws + 82 * MB);   // 2M
    bf16* WIHB  = (bf16*)(ws + 84 * MB);   // 6M
    bf16* WIPT  = (bf16*)(ws + 90 * MB);   // 2M
    bf16* T1T   = (bf16*)(ws + 92 * MB);   // 2M
    bf16* T2T   = (bf16*)(ws + 94 * MB);   // 2M
    bf16* WFGB  = (bf16*)(ws + 96 * MB);   // 4M
    float* T1B  = (float*)(ws + 100 * MB);
    float* T2B  = (float*)(ws + 100 * MB + 8192);
    float* T3B  = (float*)(ws + 100 * MB + 16384);
    bf16* GATED = (bf16*)(ws + 128 * MB);  // [128,144M); becomes UPD in place
    bf16* WCOMB = (bf16*)(ws + 144 * MB);  // [144,150M)
    bf16* WOGB  = (bf16*)(ws + 150 * MB);  // [150,152M)

    const int M = B_ROWS;
    dim3 blk(256);

    // 1. activations -> bf16 concat
    build_cat_k<<<dim3((M * 2048 / 4) / 256), blk, 0, stream>>>(prev, input, CAT);
    // 2. all front weight casts in one launch
    cast_weights_k<<<dim3(8192), blk, 0, stream>>>(
        in_proj_w + 2048 * 1024, out_proj_w, gih_w, fg_w, og_w,
        WVB, WOPB, WIHB, WFGB, WOGB);
    // 3. Wip^T (bf16)
    transpose_cast_k<<<dim3(32, 32), blk, 0, stream>>>(ip_w, WIPT, 1024, 1024);
    // 4. bias chain (fp32, exact)
    gemv_k<<<dim3(256), blk, 0, stream>>>(in_proj_w + 2048 * 1024, ip_b, in_proj_b + 2048, T1B, 1024);
    gemv_k<<<dim3(256), blk, 0, stream>>>(out_proj_w, T1B, out_proj_b, T2B, 1024);
    gemv_k<<<dim3(768), blk, 0, stream>>>(gih_w, T2B, gih_b, T3B, 1024);
    // 5-7. weight composition: Wcomb = Wih @ Wop @ Wv @ Wip
    gemm64_k<<<dim3(128), blk, 0, stream>>>(WVB, 1024, WIPT, 1024, nullptr,
        1024, 1024, 3, T1T, nullptr, nullptr, nullptr, 1024, 16);  // (Wv@Wip)^T
    gemm64_k<<<dim3(128), blk, 0, stream>>>(WOPB, 1024, T1T, 1024, nullptr,
        1024, 1024, 3, T2T, nullptr, nullptr, nullptr, 1024, 16);  // (Wop@..)^T
    gemm64_k<<<dim3(384), blk, 0, stream>>>(WIHB, 1024, T2T, 1024, nullptr,
        1024, 1024, 0, WCOMB, nullptr, nullptr, nullptr, 0, 48);   // Wcomb
    // 8. gated = prev * sigmoid(cat @ Wfg^T + bfg)
    gemm128_k<<<dim3(512), blk, 0, stream>>>(CAT, 2048, WFGB, 2048,
        fg_b, 1024, 2048, 1, GATED, nullptr, prev, nullptr, 0, 64);
    // 9. gi = x @ Wcomb^T + bcomb
    gemm128_k<<<dim3(1536), blk, 0, stream>>>(CAT + 1024, 2048, WCOMB,
        1024, T3B, 3072, 1024, 0, GI, nullptr, nullptr, nullptr, 0, 64);
    // 10. Whh cast (CAT now dead)
    cast_f32_bf16_k<<<dim3(3072), blk, 0, stream>>>(ghh_w, WHHB, 3072 * 1024 / 4);
    // 11. gh = gated @ Whh^T + bhh
    gemm128_k<<<dim3(1536), blk, 0, stream>>>(GATED, 1024, WHHB, 1024,
        ghh_b, 3072, 1024, 0, GH, nullptr, nullptr, nullptr, 0, 64);
    // 12. GRU combine (in place: GATED becomes UPD)
    gru_combine_k<<<dim3(M * 1024 / 8 / 256), blk, 0, stream>>>(GI, GH, GATED);
    // 13. out = upd * sigmoid(upd @ Wog^T + bog)
    gemm128_k<<<dim3(512), blk, 0, stream>>>(GATED, 1024, WOGB, 1024,
        og_b, 1024, 1024, 2, nullptr, out, nullptr, GATED, 0, 64);
    // 14. attention weights == 1.0
    fill_ones_k<<<dim3(32), blk, 0, stream>>>(out + (size_t)M * 1024, M);
}